// Round 14
// baseline (180.059 us; speedup 1.0000x reference)
//
#include <hip/hip_runtime.h>
#include <hip/hip_bf16.h>

// Problem constants (match reference)
#define NNODE_DIN 128
#define NNODE_DOUT 128
#define DEG 48
#define TOPK 32

typedef _Float16 halfx8 __attribute__((ext_vector_type(8)));
typedef unsigned short ushortx8 __attribute__((ext_vector_type(8)));
typedef float floatx4 __attribute__((ext_vector_type(4)));

__device__ inline unsigned short f2h(float f) {
    _Float16 h = (_Float16)f;
    return __builtin_bit_cast(unsigned short, h);
}
__device__ inline float h2f(unsigned short u) {
    return (float)__builtin_bit_cast(_Float16, u);
}
// Raw transcendentals: proven correct in rounds 1-13 (absmax unchanged).
__device__ inline float fast_sqrt(float x) {
    float r; asm("v_sqrt_f32 %0, %1" : "=v"(r) : "v"(x)); return r;
}
__device__ inline float fast_exp(float x) {  // e^x, x <= 0 here (no overflow path)
    float t = x * 1.44269504088896341f;
    float r; asm("v_exp_f32 %0, %1" : "=v"(r) : "v"(t)); return r;
}
__device__ inline float fast_rcp(float x) {
    float r; asm("v_rcp_f32 %0, %1" : "=v"(r) : "v"(x)); return r;
}

// ---------------------------------------------------------------------------
// Kernel 0: pre-swizzle W^T into split-FP16 MFMA B-fragments (frozen).
// ---------------------------------------------------------------------------
__global__ __launch_bounds__(256) void k0_wprep(
    const float* __restrict__ w, unsigned short* __restrict__ wth,
    unsigned short* __restrict__ wtl) {
    int tid = blockIdx.x * 256 + threadIdx.x;  // 0..2047
    int lane = tid & 63;
    int kt = (tid >> 6) & 3;
    int nt = tid >> 8;
    int m = lane & 15, q = lane >> 4;
    int nn = nt * 16 + m;
    int k0 = kt * 32 + q * 8;
    ushortx8 uh, ul;
#pragma unroll
    for (int e = 0; e < 8; ++e) {
        float v = w[(size_t)(k0 + e) * 128 + nn];
        unsigned short h = f2h(v);
        uh[e] = h;
        ul[e] = f2h(v - h2f(h));
    }
    *(ushortx8*)(wth + tid * 8) = uh;
    *(ushortx8*)(wtl + tid * 8) = ul;
}

// ---------------------------------------------------------------------------
// Kernel 1: x = feat @ W via split-FP16 MFMA. ROUND-14: nt-SPLIT ACROSS 2
// WAVES per 16-row block (wave w owns nt in [4w,4w+4)). This is BOTH a
// latency attack AND the k1-magnitude probe: the non-k2 residue (~88.7us)
// has been invariant across k1 bodies, and the two candidate models are
// (a) k1 latency-bound (long serial 96-MFMA chain, 12 waves/CU) vs (b)
// fixed harness overhead. This halves the per-wave chain (48 MFMAs) and
// doubles waves (24/CU) with only 2x A-prep duplication (r7's regression
// was 4x dup + restructure; the cost here is quartered, L1 should absorb
// most of the duplicate feat loads). xf output is BIT-IDENTICAL to r13
// (same per-nt MFMA sequence) -> absmax must stay exactly 0.01953125.
// Readout: total time. (a) -> ~156-168us; (b) -> flat.
// ---------------------------------------------------------------------------
__global__ __launch_bounds__(128, 4) void k1_mfma(
    const float* __restrict__ feat, const unsigned short* __restrict__ wth,
    const unsigned short* __restrict__ wtl, unsigned short* __restrict__ xf,
    int n) {
    __shared__ float s_x[16 * 132];
    int t = threadIdx.x;
    int w = t >> 6;   // wave 0..1
    int l = t & 63;
    int m = l & 15, q = l >> 4;
    int r0 = blockIdx.x * 16;

    // A-prep: both waves load/convert the same 16 rows (wave 1's loads are
    // L1/L2 hits; the cvt VALU duplication is ~150 insts, cheap).
    halfx8 ah[4], al[4];
#pragma unroll
    for (int kt = 0; kt < 4; ++kt) {
        float vv[8];
        if (r0 + m < n) {
            const float* src = feat + (size_t)(r0 + m) * 128 + kt * 32 + q * 8;
            float4 v0 = *(const float4*)src;
            float4 v1 = *(const float4*)(src + 4);
            vv[0] = v0.x; vv[1] = v0.y; vv[2] = v0.z; vv[3] = v0.w;
            vv[4] = v1.x; vv[5] = v1.y; vv[6] = v1.z; vv[7] = v1.w;
        } else {
#pragma unroll
            for (int e = 0; e < 8; ++e) vv[e] = 0.0f;
        }
        ushortx8 uh, ul;
#pragma unroll
        for (int e = 0; e < 8; ++e) {
            unsigned short h = f2h(vv[e]);
            uh[e] = h;
            ul[e] = f2h(vv[e] - h2f(h));
        }
        ah[kt] = __builtin_bit_cast(halfx8, uh);
        al[kt] = __builtin_bit_cast(halfx8, ul);
    }

    // nt-split: wave w computes nt in [4w, 4w+4). Same per-nt body as r13.
#pragma unroll 2
    for (int nn = 0; nn < 4; ++nn) {
        int nt = 4 * w + nn;
        floatx4 a = (floatx4){0.f, 0.f, 0.f, 0.f};
#pragma unroll
        for (int kt = 0; kt < 4; ++kt) {
            int fo = ((nt * 4 + kt) * 64 + l) * 8;
            halfx8 bh = *(const halfx8*)(wth + fo);
            halfx8 bl = *(const halfx8*)(wtl + fo);
            a = __builtin_amdgcn_mfma_f32_16x16x32_f16(ah[kt], bh, a, 0, 0, 0);
            a = __builtin_amdgcn_mfma_f32_16x16x32_f16(ah[kt], bl, a, 0, 0, 0);
            a = __builtin_amdgcn_mfma_f32_16x16x32_f16(al[kt], bh, a, 0, 0, 0);
        }
        // Waves write disjoint column ranges (wave 0: cols 0-63, wave 1:
        // 64-127); rows full. No race.
#pragma unroll
        for (int r = 0; r < 4; ++r)
            s_x[(q * 4 + r) * 132 + nt * 16 + m] = a[r];
    }
    __syncthreads();

    // Epilogue: 128 threads, thread t -> row t>>3, cols (t&7)*16..+15
    // (r7-proven mapping at half scale); two uint4 stores.
    {
        int row = t >> 3;
        int c0 = (t & 7) * 16;
        if (r0 + row < n) {
            float vv[16];
#pragma unroll
            for (int j = 0; j < 4; ++j) {
                float4 v = *(const float4*)&s_x[row * 132 + c0 + j * 4];
                vv[j * 4 + 0] = v.x; vv[j * 4 + 1] = v.y;
                vv[j * 4 + 2] = v.z; vv[j * 4 + 3] = v.w;
            }
            unsigned u[8];
#pragma unroll
            for (int p = 0; p < 8; ++p) {
                u[p] = (unsigned)f2h(vv[2 * p]) | ((unsigned)f2h(vv[2 * p + 1]) << 16);
            }
            size_t off = (size_t)(r0 + row) * 128 + c0;
            *(uint4*)(xf + off) = make_uint4(u[0], u[1], u[2], u[3]);
            *(uint4*)(xf + off + 8) = make_uint4(u[4], u[5], u[6], u[7]);
        }
    }
}

// ---------------------------------------------------------------------------
// Kernel 2: ROUND-13 VERBATIM (best: 87.5us, passed; balanced-pipe regime —
// VALU 62 / HBM 27 / MFMA 6, occ 80; near its practical floor for this
// structure). FROZEN this round.
// ---------------------------------------------------------------------------
__global__ __launch_bounds__(128, 4) void k2_conv(
    const float* __restrict__ ew, const int* __restrict__ nbr,
    const float* __restrict__ bias, const unsigned short* __restrict__ xf,
    float* __restrict__ outp, int n) {
    __shared__ float s_tw[32];
    __shared__ int s_id[32];
    __shared__ float s_diag[32];
    __shared__ float s_dist[32];
    __shared__ float s_omega[32];
    __shared__ _Float16 s_rows[32][136];  // padded stride (r7-proven, ~0 confl)

    int i = blockIdx.x;
    int t = threadIdx.x;
    int w = t >> 6;   // wave 0..1
    int l = t & 63;

    // A+B: register top-k (exact jax.lax.top_k tie semantics), WAVE 0 ONLY.
    if (w == 0) {
        float wj = -1.0f;  // sentinel for lanes 49-63 (rank >= 49, never written)
        int nbv = 0;
        if (l < DEG) {
            wj = ew[(size_t)i * DEG + l];
            nbv = nbr[(size_t)i * DEG + l];
        } else if (l == DEG) {
            wj = 1.0f;
            nbv = i;
        }
        int rank = 0;
#pragma unroll
        for (int t2 = 0; t2 <= DEG; ++t2) {
            int wti = __builtin_amdgcn_readlane(__builtin_bit_cast(int, wj), t2);
            float wt = __builtin_bit_cast(float, wti);
            rank += ((wt > wj) || ((wt == wj) && (t2 < l))) ? 1 : 0;
        }
        if (l <= DEG && rank < TOPK) {
            s_tw[rank] = wj;
            s_id[rank] = nbv;
        }
    }
    __syncthreads();

    // C: gather in direct MFMA layout (r8 mapping). Wave w owns rows
    // [16w,16w+16); lane (m,q) fetches row s_id[a0+m], slice q*8+kt*32.
    int m = l & 15;
    int q = l >> 4;
    int a0 = w * 16;
    int o0 = 16 - a0;
    int rowg = s_id[a0 + m];
    const _Float16* gp = (const _Float16*)xf + (size_t)rowg * 128 + q * 8;

    halfx8 Hown[4];
#pragma unroll
    for (int kt = 0; kt < 4; ++kt) Hown[kt] = *(const halfx8*)(gp + kt * 32);
#pragma unroll
    for (int kt = 0; kt < 4; ++kt)
        *(halfx8*)&s_rows[a0 + m][kt * 32 + q * 8] = Hown[kt];
    __syncthreads();

    // D: other wave's rows from LDS; own rows from registers.
    halfx8 Hoth[4];
#pragma unroll
    for (int kt = 0; kt < 4; ++kt)
        Hoth[kt] = *(const halfx8*)&s_rows[o0 + m][kt * 32 + q * 8];

    floatx4 accO = (floatx4){0.f, 0.f, 0.f, 0.f};  // G[a0+i][a0+j]
    floatx4 accX = (floatx4){0.f, 0.f, 0.f, 0.f};  // G[a0+i][o0+j]
#pragma unroll
    for (int kt = 0; kt < 4; ++kt) {
        accO = __builtin_amdgcn_mfma_f32_16x16x32_f16(Hown[kt], Hown[kt], accO, 0, 0, 0);
        accX = __builtin_amdgcn_mfma_f32_16x16x32_f16(Hown[kt], Hoth[kt], accX, 0, 0, 0);
    }

    // D2: diagonal from own quadrant (row==col -> d2_aa == 0 exactly)
    if (q == (m >> 2)) {
        s_diag[a0 + m] = accO[m & 3];
    }
    __syncthreads();

    // E: dist[a] = sum over all 32 b of tw[b]*sqrt(d2>0 ? d2 : 0), a in own 16
    {
        float dbO = s_diag[a0 + m];
        float dbX = s_diag[o0 + m];
        float twO = s_tw[a0 + m];
        float twX = s_tw[o0 + m];
#pragma unroll
        for (int r = 0; r < 4; ++r) {
            int a = a0 + q * 4 + r;
            float da = s_diag[a];
            float d2o = da + dbO - 2.0f * accO[r];
            float d2x = da + dbX - 2.0f * accX[r];
            float t0 = (d2o > 0.0f) ? fast_sqrt(d2o) : 0.0f;
            float t1 = (d2x > 0.0f) ? fast_sqrt(d2x) : 0.0f;
            float v = twO * t0 + twX * t1;
            v += __shfl_xor(v, 1);
            v += __shfl_xor(v, 2);
            v += __shfl_xor(v, 4);
            v += __shfl_xor(v, 8);
            if (m == 0) s_dist[a] = v;
        }
    }
    __syncthreads();

    // F: omega = exp(-dist - max(-dist)) * tw, normalized (wave 0 computes)
    if (w == 0) {
        int k32 = l & 31;
        float s = s_dist[k32];
        float mn = s;
        mn = fminf(mn, __shfl_xor(mn, 1));
        mn = fminf(mn, __shfl_xor(mn, 2));
        mn = fminf(mn, __shfl_xor(mn, 4));
        mn = fminf(mn, __shfl_xor(mn, 8));
        mn = fminf(mn, __shfl_xor(mn, 16));
        float e = fast_exp(mn - s) * s_tw[k32];
        float sum = e;
        sum += __shfl_xor(sum, 1);
        sum += __shfl_xor(sum, 2);
        sum += __shfl_xor(sum, 4);
        sum += __shfl_xor(sum, 8);
        sum += __shfl_xor(sum, 16);
        float om = e * fast_rcp(sum);
        if (l < 32) s_omega[l] = om;
    }
    __syncthreads();

    // G: thread t owns output column t; read s_rows[b][t] (2 lanes/bank =
    // free) with broadcast s_omega[b]. One coalesced float store per thread.
    {
        float o = bias[t];
#pragma unroll
        for (int b = 0; b < 32; ++b) {
            o += s_omega[b] * (float)s_rows[b][t];
        }
        outp[(size_t)i * 128 + t] = o;
    }
}

extern "C" void kernel_launch(void* const* d_in, const int* in_sizes, int n_in,
                              void* d_out, int out_size, void* d_ws, size_t ws_size,
                              hipStream_t stream) {
    const float* feat = (const float*)d_in[0];
    const float* ew = (const float*)d_in[1];
    const float* weight = (const float*)d_in[2];
    const float* bias = (const float*)d_in[3];
    const int* nbr = (const int*)d_in[4];
    float* outp = (float*)d_out;
    int n = in_sizes[0] / NNODE_DIN;  // 50000

    unsigned short* xf = (unsigned short*)d_ws;            // n x 128 fp16
    unsigned short* wth = xf + (size_t)n * NNODE_DOUT;     // 2048 frags x 16B
    unsigned short* wtl = wth + 2048 * 8;

    hipLaunchKernelGGL(k0_wprep, dim3(8), dim3(256), 0, stream, weight, wth, wtl);
    int grid1 = (n + 15) / 16;
    hipLaunchKernelGGL(k1_mfma, dim3(grid1), dim3(128), 0, stream, feat, wth, wtl, xf, n);
    hipLaunchKernelGGL(k2_conv, dim3(n), dim3(128), 0, stream, ew, nbr, bias, xf, outp, n);
}

// Round 15
// 175.066 us; speedup vs baseline: 1.0285x; 1.0285x over previous
//
#include <hip/hip_runtime.h>
#include <hip/hip_bf16.h>

// Problem constants (match reference)
#define NNODE_DIN 128
#define NNODE_DOUT 128
#define DEG 48
#define TOPK 32

typedef _Float16 halfx8 __attribute__((ext_vector_type(8)));
typedef unsigned short ushortx8 __attribute__((ext_vector_type(8)));
typedef float floatx4 __attribute__((ext_vector_type(4)));

__device__ inline unsigned short f2h(float f) {
    _Float16 h = (_Float16)f;
    return __builtin_bit_cast(unsigned short, h);
}
__device__ inline float h2f(unsigned short u) {
    return (float)__builtin_bit_cast(_Float16, u);
}
// Raw transcendentals: proven correct in rounds 1-14 (absmax unchanged).
__device__ inline float fast_sqrt(float x) {
    float r; asm("v_sqrt_f32 %0, %1" : "=v"(r) : "v"(x)); return r;
}
__device__ inline float fast_exp(float x) {  // e^x, x <= 0 here (no overflow path)
    float t = x * 1.44269504088896341f;
    float r; asm("v_exp_f32 %0, %1" : "=v"(r) : "v"(t)); return r;
}
__device__ inline float fast_rcp(float x) {
    float r; asm("v_rcp_f32 %0, %1" : "=v"(r) : "v"(x)); return r;
}

// ---------------------------------------------------------------------------
// Kernel 0: pre-swizzle W^T into split-FP16 MFMA B-fragments (frozen; wtl
// still needed for the ah*bl correction term in k1).
// ---------------------------------------------------------------------------
__global__ __launch_bounds__(256) void k0_wprep(
    const float* __restrict__ w, unsigned short* __restrict__ wth,
    unsigned short* __restrict__ wtl) {
    int tid = blockIdx.x * 256 + threadIdx.x;  // 0..2047
    int lane = tid & 63;
    int kt = (tid >> 6) & 3;
    int nt = tid >> 8;
    int m = lane & 15, q = lane >> 4;
    int nn = nt * 16 + m;
    int k0 = kt * 32 + q * 8;
    ushortx8 uh, ul;
#pragma unroll
    for (int e = 0; e < 8; ++e) {
        float v = w[(size_t)(k0 + e) * 128 + nn];
        unsigned short h = f2h(v);
        uh[e] = h;
        ul[e] = f2h(v - h2f(h));
    }
    *(ushortx8*)(wth + tid * 8) = uh;
    *(ushortx8*)(wtl + tid * 8) = ul;
}

// ---------------------------------------------------------------------------
// Kernel 1: x = feat @ W. ROUND-15: back to the r13 single-wave shape (r14's
// 2-wave split measured -3.8us; r7's 4-wave -13us — chain length is NOT the
// k1 limiter) with ONE change: A-RESIDUAL DROPPED. x ~= ah*(bh+bl): the
// omitted al*(bh+bl) term is bounded by |feat|*2^-11*|W|*sqrt(128) ~ 5.4e-4
// on x — same order as the existing fp16 storage quantization (7e-4) that
// yields absmax 0.0195 vs threshold 0.0819. MFMAs 96->64/wave, A-prep VALU
// halves, -16 VGPR. Doubles as the final k1-magnitude probe: if -33% MFMA
// doesn't move the total, k1 is small and the residue is fixed overhead.
// ---------------------------------------------------------------------------
__global__ __launch_bounds__(64, 4) void k1_mfma(
    const float* __restrict__ feat, const unsigned short* __restrict__ wth,
    const unsigned short* __restrict__ wtl, unsigned short* __restrict__ xf,
    int n) {
    __shared__ float s_x[16 * 132];
    int l = threadIdx.x;
    int m = l & 15, q = l >> 4;
    int r0 = blockIdx.x * 16;

    halfx8 ah[4];
#pragma unroll
    for (int kt = 0; kt < 4; ++kt) {
        float vv[8];
        if (r0 + m < n) {
            const float* src = feat + (size_t)(r0 + m) * 128 + kt * 32 + q * 8;
            float4 v0 = *(const float4*)src;
            float4 v1 = *(const float4*)(src + 4);
            vv[0] = v0.x; vv[1] = v0.y; vv[2] = v0.z; vv[3] = v0.w;
            vv[4] = v1.x; vv[5] = v1.y; vv[6] = v1.z; vv[7] = v1.w;
        } else {
#pragma unroll
            for (int e = 0; e < 8; ++e) vv[e] = 0.0f;
        }
        ushortx8 uh;
#pragma unroll
        for (int e = 0; e < 8; ++e) uh[e] = f2h(vv[e]);
        ah[kt] = __builtin_bit_cast(halfx8, uh);
    }

#pragma unroll 2
    for (int nt = 0; nt < 8; ++nt) {
        floatx4 a = (floatx4){0.f, 0.f, 0.f, 0.f};
#pragma unroll
        for (int kt = 0; kt < 4; ++kt) {
            int fo = ((nt * 4 + kt) * 64 + l) * 8;
            halfx8 bh = *(const halfx8*)(wth + fo);
            halfx8 bl = *(const halfx8*)(wtl + fo);
            a = __builtin_amdgcn_mfma_f32_16x16x32_f16(ah[kt], bh, a, 0, 0, 0);
            a = __builtin_amdgcn_mfma_f32_16x16x32_f16(ah[kt], bl, a, 0, 0, 0);
        }
#pragma unroll
        for (int r = 0; r < 4; ++r)
            s_x[(q * 4 + r) * 132 + nt * 16 + m] = a[r];
    }
    __syncthreads();

#pragma unroll
    for (int rr = 0; rr < 2; ++rr) {
        int row = rr * 8 + (l >> 3);
        int c0 = (l & 7) * 16;
        if (r0 + row < n) {
            float vv[16];
#pragma unroll
            for (int j = 0; j < 4; ++j) {
                float4 v = *(const float4*)&s_x[row * 132 + c0 + j * 4];
                vv[j * 4 + 0] = v.x; vv[j * 4 + 1] = v.y;
                vv[j * 4 + 2] = v.z; vv[j * 4 + 3] = v.w;
            }
            unsigned u[8];
#pragma unroll
            for (int p = 0; p < 8; ++p) {
                u[p] = (unsigned)f2h(vv[2 * p]) | ((unsigned)f2h(vv[2 * p + 1]) << 16);
            }
            size_t off = (size_t)(r0 + row) * 128 + c0;
            *(uint4*)(xf + off) = make_uint4(u[0], u[1], u[2], u[3]);
            *(uint4*)(xf + off + 8) = make_uint4(u[4], u[5], u[6], u[7]);
        }
    }
}

// ---------------------------------------------------------------------------
// Kernel 2: ROUND-13 VERBATIM (best: 87.5us, passed; balanced-pipe regime —
// VALU 62 / HBM 27 / MFMA 6, occ 80; near its practical floor for this
// structure). FROZEN.
// ---------------------------------------------------------------------------
__global__ __launch_bounds__(128, 4) void k2_conv(
    const float* __restrict__ ew, const int* __restrict__ nbr,
    const float* __restrict__ bias, const unsigned short* __restrict__ xf,
    float* __restrict__ outp, int n) {
    __shared__ float s_tw[32];
    __shared__ int s_id[32];
    __shared__ float s_diag[32];
    __shared__ float s_dist[32];
    __shared__ float s_omega[32];
    __shared__ _Float16 s_rows[32][136];  // padded stride (r7-proven, ~0 confl)

    int i = blockIdx.x;
    int t = threadIdx.x;
    int w = t >> 6;   // wave 0..1
    int l = t & 63;

    // A+B: register top-k (exact jax.lax.top_k tie semantics), WAVE 0 ONLY.
    if (w == 0) {
        float wj = -1.0f;  // sentinel for lanes 49-63 (rank >= 49, never written)
        int nbv = 0;
        if (l < DEG) {
            wj = ew[(size_t)i * DEG + l];
            nbv = nbr[(size_t)i * DEG + l];
        } else if (l == DEG) {
            wj = 1.0f;
            nbv = i;
        }
        int rank = 0;
#pragma unroll
        for (int t2 = 0; t2 <= DEG; ++t2) {
            int wti = __builtin_amdgcn_readlane(__builtin_bit_cast(int, wj), t2);
            float wt = __builtin_bit_cast(float, wti);
            rank += ((wt > wj) || ((wt == wj) && (t2 < l))) ? 1 : 0;
        }
        if (l <= DEG && rank < TOPK) {
            s_tw[rank] = wj;
            s_id[rank] = nbv;
        }
    }
    __syncthreads();

    // C: gather in direct MFMA layout (r8 mapping). Wave w owns rows
    // [16w,16w+16); lane (m,q) fetches row s_id[a0+m], slice q*8+kt*32.
    int m = l & 15;
    int q = l >> 4;
    int a0 = w * 16;
    int o0 = 16 - a0;
    int rowg = s_id[a0 + m];
    const _Float16* gp = (const _Float16*)xf + (size_t)rowg * 128 + q * 8;

    halfx8 Hown[4];
#pragma unroll
    for (int kt = 0; kt < 4; ++kt) Hown[kt] = *(const halfx8*)(gp + kt * 32);
#pragma unroll
    for (int kt = 0; kt < 4; ++kt)
        *(halfx8*)&s_rows[a0 + m][kt * 32 + q * 8] = Hown[kt];
    __syncthreads();

    // D: other wave's rows from LDS; own rows from registers.
    halfx8 Hoth[4];
#pragma unroll
    for (int kt = 0; kt < 4; ++kt)
        Hoth[kt] = *(const halfx8*)&s_rows[o0 + m][kt * 32 + q * 8];

    floatx4 accO = (floatx4){0.f, 0.f, 0.f, 0.f};  // G[a0+i][a0+j]
    floatx4 accX = (floatx4){0.f, 0.f, 0.f, 0.f};  // G[a0+i][o0+j]
#pragma unroll
    for (int kt = 0; kt < 4; ++kt) {
        accO = __builtin_amdgcn_mfma_f32_16x16x32_f16(Hown[kt], Hown[kt], accO, 0, 0, 0);
        accX = __builtin_amdgcn_mfma_f32_16x16x32_f16(Hown[kt], Hoth[kt], accX, 0, 0, 0);
    }

    // D2: diagonal from own quadrant (row==col -> d2_aa == 0 exactly)
    if (q == (m >> 2)) {
        s_diag[a0 + m] = accO[m & 3];
    }
    __syncthreads();

    // E: dist[a] = sum over all 32 b of tw[b]*sqrt(d2>0 ? d2 : 0), a in own 16
    {
        float dbO = s_diag[a0 + m];
        float dbX = s_diag[o0 + m];
        float twO = s_tw[a0 + m];
        float twX = s_tw[o0 + m];
#pragma unroll
        for (int r = 0; r < 4; ++r) {
            int a = a0 + q * 4 + r;
            float da = s_diag[a];
            float d2o = da + dbO - 2.0f * accO[r];
            float d2x = da + dbX - 2.0f * accX[r];
            float t0 = (d2o > 0.0f) ? fast_sqrt(d2o) : 0.0f;
            float t1 = (d2x > 0.0f) ? fast_sqrt(d2x) : 0.0f;
            float v = twO * t0 + twX * t1;
            v += __shfl_xor(v, 1);
            v += __shfl_xor(v, 2);
            v += __shfl_xor(v, 4);
            v += __shfl_xor(v, 8);
            if (m == 0) s_dist[a] = v;
        }
    }
    __syncthreads();

    // F: omega = exp(-dist - max(-dist)) * tw, normalized (wave 0 computes)
    if (w == 0) {
        int k32 = l & 31;
        float s = s_dist[k32];
        float mn = s;
        mn = fminf(mn, __shfl_xor(mn, 1));
        mn = fminf(mn, __shfl_xor(mn, 2));
        mn = fminf(mn, __shfl_xor(mn, 4));
        mn = fminf(mn, __shfl_xor(mn, 8));
        mn = fminf(mn, __shfl_xor(mn, 16));
        float e = fast_exp(mn - s) * s_tw[k32];
        float sum = e;
        sum += __shfl_xor(sum, 1);
        sum += __shfl_xor(sum, 2);
        sum += __shfl_xor(sum, 4);
        sum += __shfl_xor(sum, 8);
        sum += __shfl_xor(sum, 16);
        float om = e * fast_rcp(sum);
        if (l < 32) s_omega[l] = om;
    }
    __syncthreads();

    // G: thread t owns output column t; read s_rows[b][t] (2 lanes/bank =
    // free) with broadcast s_omega[b]. One coalesced float store per thread.
    {
        float o = bias[t];
#pragma unroll
        for (int b = 0; b < 32; ++b) {
            o += s_omega[b] * (float)s_rows[b][t];
        }
        outp[(size_t)i * 128 + t] = o;
    }
}

extern "C" void kernel_launch(void* const* d_in, const int* in_sizes, int n_in,
                              void* d_out, int out_size, void* d_ws, size_t ws_size,
                              hipStream_t stream) {
    const float* feat = (const float*)d_in[0];
    const float* ew = (const float*)d_in[1];
    const float* weight = (const float*)d_in[2];
    const float* bias = (const float*)d_in[3];
    const int* nbr = (const int*)d_in[4];
    float* outp = (float*)d_out;
    int n = in_sizes[0] / NNODE_DIN;  // 50000

    unsigned short* xf = (unsigned short*)d_ws;            // n x 128 fp16
    unsigned short* wth = xf + (size_t)n * NNODE_DOUT;     // 2048 frags x 16B
    unsigned short* wtl = wth + 2048 * 8;

    hipLaunchKernelGGL(k0_wprep, dim3(8), dim3(256), 0, stream, weight, wth, wtl);
    int grid1 = (n + 15) / 16;
    hipLaunchKernelGGL(k1_mfma, dim3(grid1), dim3(64), 0, stream, feat, wth, wtl, xf, n);
    hipLaunchKernelGGL(k2_conv, dim3(n), dim3(128), 0, stream, ew, nbr, bias, xf, outp, n);
}